// Round 1
// baseline (162.991 us; speedup 1.0000x reference)
//
#include <hip/hip_runtime.h>
#include <hip/hip_bf16.h>
#include <stdint.h>

#define VOCAB 100000
#define SEQ   8192
#define BATCH 8
#define DIM   128

typedef short bf16x8 __attribute__((ext_vector_type(8)));
typedef float f32x4  __attribute__((ext_vector_type(4)));

__device__ __forceinline__ ushort f2bf(float f) {
  union { float f; uint32_t u; } v; v.f = f;
  uint32_t u = v.u;
  return (ushort)((u + 0x7FFF + ((u >> 16) & 1)) >> 16);  // RNE; inputs never NaN
}

// ---------------------------------------------------------------------------
// Pre-kernel 1: W_conv (d,i,k) fp32 -> wcb[k][d][i] bf16  (160 KB, L2-hot B)
// ---------------------------------------------------------------------------
__global__ void repack_wconv(const float* __restrict__ wconv,
                             ushort* __restrict__ wcb) {
  int e = blockIdx.x * 256 + threadIdx.x;          // 5*128*128 = 81920
  if (e >= 5 * DIM * DIM) return;
  int k = e / (DIM * DIM);
  int rem = e % (DIM * DIM);
  int d = rem / DIM, i = rem % DIM;
  wcb[e] = f2bf(wconv[(d * DIM + i) * 5 + k]);
}

// ---------------------------------------------------------------------------
// Pre-kernel 2: W_lin (dim, vocab) fp32 -> wlt[t][i] = bf16(W_lin[i][t]+b_lin[i])
// thread t: 128 coalesced reads (lane-contiguous over t), one 256B row write.
// ---------------------------------------------------------------------------
__global__ void build_wlt(const float* __restrict__ wlin,
                          const float* __restrict__ blin,
                          ushort* __restrict__ wlt) {
  int t = blockIdx.x * 256 + threadIdx.x;
  if (t >= VOCAB) return;
#pragma unroll
  for (int c = 0; c < 16; ++c) {
    ushort u[8];
#pragma unroll
    for (int j = 0; j < 8; ++j)
      u[j] = f2bf(wlin[(size_t)(c * 8 + j) * VOCAB + t] + blin[c * 8 + j]);
    *(uint4*)(wlt + (size_t)t * DIM + c * 8) = *(const uint4*)u;
  }
}

// ---------------------------------------------------------------------------
// Main: per block: 128 positions x 128 out-channels.
// LDS A-tile: 132 emb rows (halo +-2) x 128 bf16, pitch 136 ushorts (272 B)
//   -> ds_read_b128 bank pattern (17r+q)%32, conflict-free.
// Conv tap k == A-tile row shift k: 5 accumulated K=128 GEMMs, one staging.
// B fragments straight from global (wcb, L2-hot), 16 frags (64 VGPRs) per k.
// ---------------------------------------------------------------------------
__global__ __launch_bounds__(256, 2) void conv_main(
    const int* __restrict__ X, const ushort* __restrict__ wlt,
    const ushort* __restrict__ wcb, const float* __restrict__ bconv,
    const float* __restrict__ pos, float* __restrict__ out,
    const float* __restrict__ wlin, const float* __restrict__ blin) {
  __shared__ __align__(16) ushort Atile[132 * 136];

  const int tid   = threadIdx.x;
  const int bm    = blockIdx.x;                 // 0..511
  const int batch = bm >> 6;
  const int nbase = (bm & 63) << 7;
  const int* Xb   = X + batch * SEQ;

  // ---- stage A: 132 rows x 16 chunks of 16B; tokens first, then gathers ----
  int  tok[9];
  bool valid[9];
#pragma unroll
  for (int it = 0; it < 9; ++it) {
    int c = tid + it * 256;
    int r = c >> 4;
    int n = nbase - 2 + r;
    bool v = (c < 2112) && (n >= 0) && (n < SEQ);
    valid[it] = v;
    tok[it] = v ? Xb[n] : 0;
  }
  if (wlt) {
    uint4 val[9];
#pragma unroll
    for (int it = 0; it < 9; ++it) {
      int c = tid + it * 256;
      int ch = c & 15;
      val[it] = valid[it] ? *(const uint4*)(wlt + (size_t)tok[it] * DIM + ch * 8)
                          : make_uint4(0u, 0u, 0u, 0u);
    }
#pragma unroll
    for (int it = 0; it < 9; ++it) {
      int c = tid + it * 256;
      if (c < 2112) {
        int r = c >> 4, ch = c & 15;
        *(uint4*)&Atile[r * 136 + ch * 8] = val[it];
      }
    }
  } else {
    // fallback (workspace too small): strided column gather from W_lin
#pragma unroll
    for (int it = 0; it < 9; ++it) {
      int c = tid + it * 256;
      if (c >= 2112) continue;
      int r = c >> 4, ch = c & 15;
      ushort u[8];
#pragma unroll
      for (int j = 0; j < 8; ++j) {
        int i = ch * 8 + j;
        float f = valid[it] ? (wlin[(size_t)i * VOCAB + tok[it]] + blin[i]) : 0.f;
        u[j] = f2bf(f);
      }
      *(uint4*)&Atile[r * 136 + ch * 8] = *(const uint4*)u;
    }
  }
  __syncthreads();

  // ---- compute: 4 waves, each 64x64 = 4x4 frags of 16x16x32 bf16 ----
  const int wave = tid >> 6;
  const int lane = tid & 63;
  const int wm = (wave >> 1) << 6;
  const int wn = (wave & 1) << 6;
  const int lr = lane & 15;   // A: m-index / B,C: n-index
  const int lq = lane >> 4;   // quad

  f32x4 acc[4][4];
#pragma unroll
  for (int a = 0; a < 4; ++a)
#pragma unroll
    for (int b = 0; b < 4; ++b) acc[a][b] = (f32x4)0.f;

#pragma unroll
  for (int k = 0; k < 5; ++k) {
    bf16x8 B[4][4];  // [nt][kk]
#pragma unroll
    for (int nt = 0; nt < 4; ++nt)
#pragma unroll
      for (int kk = 0; kk < 4; ++kk)
        B[nt][kk] = *(const bf16x8*)(wcb +
            ((size_t)(k * DIM + wn + nt * 16 + lr) * DIM + kk * 32 + lq * 8));
#pragma unroll
    for (int kk = 0; kk < 4; ++kk) {
      bf16x8 A[4];
#pragma unroll
      for (int mt = 0; mt < 4; ++mt)
        A[mt] = *(const bf16x8*)&Atile[(wm + mt * 16 + lr + k) * 136 + kk * 32 + lq * 8];
#pragma unroll
      for (int mt = 0; mt < 4; ++mt)
#pragma unroll
        for (int nt = 0; nt < 4; ++nt)
          acc[mt][nt] = __builtin_amdgcn_mfma_f32_16x16x32_bf16(
              A[mt], B[nt][kk], acc[mt][nt], 0, 0, 0);
    }
  }

  // ---- epilogue: + b_conv[d] + pos[n][d]; C layout col=lane&15, row=lq*4+rr ----
  float bc[4];
#pragma unroll
  for (int nt = 0; nt < 4; ++nt) bc[nt] = bconv[wn + nt * 16 + lr];
  float* outb = out + (size_t)batch * SEQ * DIM;
#pragma unroll
  for (int mt = 0; mt < 4; ++mt) {
#pragma unroll
    for (int rr = 0; rr < 4; ++rr) {
      int m = wm + mt * 16 + lq * 4 + rr;
      int gn = nbase + m;
      const float* posrow = pos + (size_t)gn * DIM;
      float* orow = outb + (size_t)gn * DIM;
#pragma unroll
      for (int nt = 0; nt < 4; ++nt) {
        int d = wn + nt * 16 + lr;
        orow[d] = acc[mt][nt][rr] + bc[nt] + posrow[d];
      }
    }
  }
}

// ---------------------------------------------------------------------------
extern "C" void kernel_launch(void* const* d_in, const int* in_sizes, int n_in,
                              void* d_out, int out_size, void* d_ws, size_t ws_size,
                              hipStream_t stream) {
  const int*   X     = (const int*)d_in[0];
  const float* wlin  = (const float*)d_in[1];
  const float* blin  = (const float*)d_in[2];
  const float* wconv = (const float*)d_in[3];
  const float* bconv = (const float*)d_in[4];
  const float* pos   = (const float*)d_in[5];
  float*       out   = (float*)d_out;

  ushort* wcb = (ushort*)d_ws;  // 163,840 B
  ushort* wlt = nullptr;
  size_t need = 262144 + (size_t)VOCAB * DIM * 2;  // ~25.9 MB
  if (ws_size >= need) wlt = (ushort*)((char*)d_ws + 262144);

  hipLaunchKernelGGL(repack_wconv, dim3(320), dim3(256), 0, stream, wconv, wcb);
  if (wlt)
    hipLaunchKernelGGL(build_wlt, dim3((VOCAB + 255) / 256), dim3(256), 0, stream,
                       wlin, blin, wlt);
  hipLaunchKernelGGL(conv_main, dim3(512), dim3(256), 0, stream,
                     X, wlt, wcb, bconv, pos, out, wlin, blin);
}

// Round 2
// 144.631 us; speedup vs baseline: 1.1269x; 1.1269x over previous
//
#include <hip/hip_runtime.h>
#include <hip/hip_bf16.h>
#include <stdint.h>

#define VOCAB 100000
#define SEQ   8192
#define BATCH 8
#define DIM   128

typedef short bf16x8 __attribute__((ext_vector_type(8)));
typedef float f32x4  __attribute__((ext_vector_type(4)));

__device__ __forceinline__ ushort f2bf(float f) {
  union { float f; uint32_t u; } v; v.f = f;
  uint32_t u = v.u;
  return (ushort)((u + 0x7FFF + ((u >> 16) & 1)) >> 16);  // RNE; inputs never NaN
}

// ---------------------------------------------------------------------------
// Pre-kernel 1: W_conv (d,i,k) fp32 -> wcb[k][d][i] bf16  (160 KB, L2-hot B)
// ---------------------------------------------------------------------------
__global__ void repack_wconv(const float* __restrict__ wconv,
                             ushort* __restrict__ wcb) {
  int e = blockIdx.x * 256 + threadIdx.x;          // 5*128*128 = 81920
  if (e >= 5 * DIM * DIM) return;
  int k = e / (DIM * DIM);
  int rem = e % (DIM * DIM);
  int d = rem / DIM, i = rem % DIM;
  wcb[e] = f2bf(wconv[(d * DIM + i) * 5 + k]);
}

// ---------------------------------------------------------------------------
// Pre-kernel 2 (rewritten): LDS tile transpose.
// Block = 64 tokens x 128 dims. Phase A: float4 coalesced reads of W_lin rows
// into fp32 LDS tile (pitch 65: scatter writes 2-way/free). Phase B: transposed
// reads (4-way, cheap), +bias, ->bf16, and FULLY CONTIGUOUS 1KB/wave stores
// (lane%16 = 16B-chunk within row, lane/16 = token).
// ---------------------------------------------------------------------------
__global__ __launch_bounds__(256) void build_wlt(
    const float* __restrict__ wlin, const float* __restrict__ blin,
    ushort* __restrict__ wlt) {
  __shared__ float tile[128 * 65];
  const int tid = threadIdx.x;
  const int t0  = blockIdx.x * 64;

  // Phase A: 8 passes, each covers 16 rows x 64 cols in float4s.
  const int c4 = (tid & 15) * 4;          // column offset within tile (0..60)
  const int rbase = tid >> 4;             // 0..15
  const bool cvalid = (t0 + c4) < VOCAB;  // VOCAB%4==0 -> whole float4 in/out
#pragma unroll
  for (int p = 0; p < 8; ++p) {
    int r = p * 16 + rbase;               // dim row 0..127
    float4 v = make_float4(0.f, 0.f, 0.f, 0.f);
    if (cvalid) v = *(const float4*)(wlin + (size_t)r * VOCAB + t0 + c4);
    float* dst = &tile[r * 65 + c4];
    dst[0] = v.x; dst[1] = v.y; dst[2] = v.z; dst[3] = v.w;
  }
  __syncthreads();

  // Phase B: thread = (chunk = tid&15, token = tid>>4 + p*16)
  const int chunk = tid & 15;
  float bias8[8];
#pragma unroll
  for (int j = 0; j < 8; ++j) bias8[j] = blin[chunk * 8 + j];

#pragma unroll
  for (int p = 0; p < 4; ++p) {
    int tl = (tid >> 4) + p * 16;         // token within tile 0..63
    int t  = t0 + tl;
    if (t >= VOCAB) continue;
    ushort u[8];
#pragma unroll
    for (int j = 0; j < 8; ++j) {
      float f = tile[(chunk * 8 + j) * 65 + tl] + bias8[j];
      u[j] = f2bf(f);
    }
    *(uint4*)(wlt + (size_t)t * DIM + chunk * 8) = *(const uint4*)u;
  }
}

// ---------------------------------------------------------------------------
// Main: per block: 128 positions x 128 out-channels.
// LDS A-tile: 132 emb rows (halo +-2) x 128 bf16, pitch 136 ushorts (272 B)
//   -> ds_read_b128 bank pattern (17r+q)%32, conflict-free.
// Conv tap k == A-tile row shift k: 5 accumulated K=128 GEMMs, one staging.
// B fragments straight from global (wcb, L2-hot), 16 frags (64 VGPRs) per k.
// ---------------------------------------------------------------------------
__global__ __launch_bounds__(256, 2) void conv_main(
    const int* __restrict__ X, const ushort* __restrict__ wlt,
    const ushort* __restrict__ wcb, const float* __restrict__ bconv,
    const float* __restrict__ pos, float* __restrict__ out) {
  __shared__ __align__(16) ushort Atile[132 * 136];

  const int tid   = threadIdx.x;
  const int bm    = blockIdx.x;                 // 0..511
  const int batch = bm >> 6;
  const int nbase = (bm & 63) << 7;
  const int* Xb   = X + batch * SEQ;

  // ---- stage A: 132 rows x 16 chunks of 16B; tokens first, then gathers ----
  int  tok[9];
  bool valid[9];
#pragma unroll
  for (int it = 0; it < 9; ++it) {
    int c = tid + it * 256;
    int r = c >> 4;
    int n = nbase - 2 + r;
    bool v = (c < 2112) && (n >= 0) && (n < SEQ);
    valid[it] = v;
    tok[it] = v ? Xb[n] : 0;
  }
  uint4 val[9];
#pragma unroll
  for (int it = 0; it < 9; ++it) {
    int c = tid + it * 256;
    int ch = c & 15;
    val[it] = valid[it] ? *(const uint4*)(wlt + (size_t)tok[it] * DIM + ch * 8)
                        : make_uint4(0u, 0u, 0u, 0u);
  }
#pragma unroll
  for (int it = 0; it < 9; ++it) {
    int c = tid + it * 256;
    if (c < 2112) {
      int r = c >> 4, ch = c & 15;
      *(uint4*)&Atile[r * 136 + ch * 8] = val[it];
    }
  }
  __syncthreads();

  // ---- compute: 4 waves, each 64x64 = 4x4 frags of 16x16x32 bf16 ----
  const int wave = tid >> 6;
  const int lane = tid & 63;
  const int wm = (wave >> 1) << 6;
  const int wn = (wave & 1) << 6;
  const int lr = lane & 15;   // A: m-index / B,C: n-index
  const int lq = lane >> 4;   // quad

  f32x4 acc[4][4];
#pragma unroll
  for (int a = 0; a < 4; ++a)
#pragma unroll
    for (int b = 0; b < 4; ++b) acc[a][b] = (f32x4)0.f;

#pragma unroll
  for (int k = 0; k < 5; ++k) {
    bf16x8 B[4][4];  // [nt][kk]
#pragma unroll
    for (int nt = 0; nt < 4; ++nt)
#pragma unroll
      for (int kk = 0; kk < 4; ++kk)
        B[nt][kk] = *(const bf16x8*)(wcb +
            ((size_t)(k * DIM + wn + nt * 16 + lr) * DIM + kk * 32 + lq * 8));
#pragma unroll
    for (int kk = 0; kk < 4; ++kk) {
      bf16x8 A[4];
#pragma unroll
      for (int mt = 0; mt < 4; ++mt)
        A[mt] = *(const bf16x8*)&Atile[(wm + mt * 16 + lr + k) * 136 + kk * 32 + lq * 8];
#pragma unroll
      for (int mt = 0; mt < 4; ++mt)
#pragma unroll
        for (int nt = 0; nt < 4; ++nt)
          acc[mt][nt] = __builtin_amdgcn_mfma_f32_16x16x32_bf16(
              A[mt], B[nt][kk], acc[mt][nt], 0, 0, 0);
    }
  }

  // ---- epilogue: + b_conv[d] + pos[n][d]; C layout col=lane&15, row=lq*4+rr ----
  float bc[4];
#pragma unroll
  for (int nt = 0; nt < 4; ++nt) bc[nt] = bconv[wn + nt * 16 + lr];
  float* outb = out + (size_t)batch * SEQ * DIM;
#pragma unroll
  for (int mt = 0; mt < 4; ++mt) {
#pragma unroll
    for (int rr = 0; rr < 4; ++rr) {
      int m = wm + mt * 16 + lq * 4 + rr;
      int gn = nbase + m;
      const float* posrow = pos + (size_t)gn * DIM;
      float* orow = outb + (size_t)gn * DIM;
#pragma unroll
      for (int nt = 0; nt < 4; ++nt) {
        int d = wn + nt * 16 + lr;
        orow[d] = acc[mt][nt][rr] + bc[nt] + posrow[d];
      }
    }
  }
}

// ---------------------------------------------------------------------------
extern "C" void kernel_launch(void* const* d_in, const int* in_sizes, int n_in,
                              void* d_out, int out_size, void* d_ws, size_t ws_size,
                              hipStream_t stream) {
  const int*   X     = (const int*)d_in[0];
  const float* wlin  = (const float*)d_in[1];
  const float* blin  = (const float*)d_in[2];
  const float* wconv = (const float*)d_in[3];
  const float* bconv = (const float*)d_in[4];
  const float* pos   = (const float*)d_in[5];
  float*       out   = (float*)d_out;

  ushort* wcb = (ushort*)d_ws;                       // 163,840 B
  ushort* wlt = (ushort*)((char*)d_ws + 262144);     // 25.6 MB

  hipLaunchKernelGGL(repack_wconv, dim3(320), dim3(256), 0, stream, wconv, wcb);
  hipLaunchKernelGGL(build_wlt, dim3((VOCAB + 63) / 64), dim3(256), 0, stream,
                     wlin, blin, wlt);
  hipLaunchKernelGGL(conv_main, dim3(512), dim3(256), 0, stream,
                     X, wlt, wcb, bconv, pos, out);
}